// Round 7
// baseline (5910.277 us; speedup 1.0000x reference)
//
#include <hip/hip_runtime.h>
#include <hip/hip_cooperative_groups.h>

namespace cg = cooperative_groups;

typedef unsigned short u16;
typedef unsigned int   u32;

#define B_    128
#define N_    8192
#define HD_   256
#define X_    768          // 3*HD
#define T_    10
#define SEGS_ 8
#define SEGROWS_ 1024      // N_/SEGS_

// ---- persistent per-call state in device globals ----
__device__ float g_hh[2][B_*HD_];   // double-buffered hidden state
__device__ float g_c[B_*HD_];
__device__ float g_q[B_*HD_];
__device__ float g_pval[B_*SEGS_*3];
__device__ int   g_pidx[B_*SEGS_*3];
__device__ int   g_isf32;

struct P {
  const void *enc, *h0, *c0, *x0, *Wih, *bih, *Whh, *bhh, *Wq, *bq;
  void* out;
};

struct SmemLG { uint4 buf[2][1024]; float qs[HD_]; };   // 32KB + 1KB
struct SmemLS { float xs[X_]; float hs[HD_]; };         // 4KB
union Smem { SmemLG lg; SmemLS ls; };

#define LDSP(x) ((__attribute__((address_space(3))) void*)(x))
#define GLBP(x) ((const __attribute__((address_space(1))) void*)(x))

__device__ __forceinline__ float bf2f(u16 u){ return __uint_as_float(((u32)u)<<16); }
__device__ __forceinline__ float lo2f(u32 w){ return __uint_as_float(w<<16); }
__device__ __forceinline__ float hi2f(u32 w){ return __uint_as_float(w & 0xffff0000u); }
__device__ __forceinline__ u16 f2bf(float f){
  u32 u = __float_as_uint(f);
  u32 r = u + 0x7fffu + ((u>>16)&1u);   // RNE
  return (u16)(r>>16);
}

template<bool F32>
__device__ __forceinline__ float ld1(const void* p, size_t i){
  if constexpr (F32) return ((const float*)p)[i];
  else               return bf2f(((const u16*)p)[i]);
}

template<bool F32>
__device__ __forceinline__ void st1(void* p, size_t i, float v){
  if constexpr (F32) ((float*)p)[i] = v;
  else               ((u16*)p)[i]   = f2bf(v);
}

template<bool F32>
__device__ __forceinline__ void ld8(const void* p, size_t i, float* o){
  if constexpr (F32){
    const float4* q = (const float4*)((const float*)p + i);
    float4 a = q[0], b = q[1];
    o[0]=a.x; o[1]=a.y; o[2]=a.z; o[3]=a.w;
    o[4]=b.x; o[5]=b.y; o[6]=b.z; o[7]=b.w;
  } else {
    uint4 u = *(const uint4*)((const u16*)p + i);
    o[0]=lo2f(u.x); o[1]=hi2f(u.x); o[2]=lo2f(u.y); o[3]=hi2f(u.y);
    o[4]=lo2f(u.z); o[5]=hi2f(u.z); o[6]=lo2f(u.w); o[7]=hi2f(u.w);
  }
}

// top-3 insert, jax.lax.top_k tie-break (equal value -> lower index first)
__device__ __forceinline__ void t3ins(float v,int i,
    float&v0,int&i0,float&v1,int&i1,float&v2,int&i2){
  if (v>v0 || (v==v0 && i<i0)) { v2=v1;i2=i1; v1=v0;i1=i0; v0=v;i0=i; }
  else if (v>v1 || (v==v1 && i<i1)) { v2=v1;i2=i1; v1=v;i1=i; }
  else if (v>v2 || (v==v2 && i<i2)) { v2=v;i2=i; }
}

// ---- dtype probe ----
__global__ void k_probe(const void* enc){
  const int lane = threadIdx.x;           // 64 threads
  const u16 u = ((const u16*)enc)[lane*2];
  const float a = fabsf(bf2f(u));
  const bool inr = (a >= 0.0009765625f) && (a <= 1024.0f);
  unsigned long long m = __ballot(inr ? 1 : 0);
  if (lane==0) g_isf32 = (__popcll(m) < 32) ? 1 : 0;
}

// ============ PHASE A: LSTM gates -> h_new, c_new (vb in [0,512)) ============
// vb -> (b = vb>>2, qt = vb&3); 64 threads, thread l owns dim d = qt*64+l.
template<bool F32>
__device__ void phaseA(const P& p, int t, int vb, Smem& sm)
{
  const int b = vb>>2, qt = vb&3, l = threadIdx.x;
  const int d = qt*64 + l;
  float* xs = sm.ls.xs;
  float* hs = sm.ls.hs;
  float cd;
  if (t==0){
    for (int i=l;i<X_;i+=64)  xs[i] = ld1<F32>(p.x0,(size_t)b*X_+i);
    for (int i=l;i<HD_;i+=64) hs[i] = ld1<F32>(p.h0,(size_t)b*HD_+i);
    cd = ld1<F32>(p.c0,(size_t)b*HD_+d);
  } else {
    // all-lane redundant merge of the 24 per-segment partials
    float v0=-3.4e38f,v1=-3.4e38f,v2=-3.4e38f; int i0=-1,i1=-1,i2=-1;
    const float* pv = g_pval + b*SEGS_*3;
    const int*   pi = g_pidx + b*SEGS_*3;
    for (int s=0;s<SEGS_*3;s++) t3ins(pv[s],pi[s],v0,i0,v1,i1,v2,i2);
    if (qt==0 && l==0){
      const size_t ib=(size_t)T_*B_*N_+(size_t)(t-1)*B_*3+(size_t)b*3;
      st1<F32>(p.out,ib+0,(float)i0);
      st1<F32>(p.out,ib+1,(float)i1);
      st1<F32>(p.out,ib+2,(float)i2);
    }
    int j3[3];
    j3[0] = i0<0?0:(i0>N_-1?N_-1:i0);
    j3[1] = i1<0?0:(i1>N_-1?N_-1:i1);
    j3[2] = i2<0?0:(i2>N_-1?N_-1:i2);
    #pragma unroll
    for (int j=0;j<3;j++)
      for (int i=l;i<HD_;i+=64)
        xs[j*HD_+i] = ld1<F32>(p.enc, ((size_t)b*N_+j3[j])*HD_+i);
    for (int i=l;i<HD_;i+=64) hs[i] = g_hh[t&1][b*HD_+i];
    cd = g_c[b*HD_+d];
  }
  __syncthreads();

  float g4[4];
  #pragma unroll
  for (int gi=0;gi<4;gi++){
    const int row = gi*HD_ + d;
    float acc = ld1<F32>(p.bih,row) + ld1<F32>(p.bhh,row);
    #pragma unroll 4
    for (int kk=0;kk<X_/8;kk++){
      float w[8]; ld8<F32>(p.Wih,(size_t)row*X_+kk*8,w);
      #pragma unroll
      for (int j=0;j<8;j++) acc=fmaf(xs[kk*8+j],w[j],acc);
    }
    #pragma unroll 4
    for (int kk=0;kk<HD_/8;kk++){
      float w[8]; ld8<F32>(p.Whh,(size_t)row*HD_+kk*8,w);
      #pragma unroll
      for (int j=0;j<8;j++) acc=fmaf(hs[kk*8+j],w[j],acc);
    }
    g4[gi]=acc;
  }
  const float si_=1.f/(1.f+expf(-g4[0]));
  const float sf_=1.f/(1.f+expf(-g4[1]));
  const float tg_=tanhf(g4[2]);
  const float so_=1.f/(1.f+expf(-g4[3]));
  const float cn = sf_*cd + si_*tg_;
  const float hv = so_*tanhf(cn);
  g_c[b*HD_+d]          = cn;
  g_hh[(t+1)&1][b*HD_+d]= hv;
  __syncthreads();   // LDS reuse across grid-stride iterations
}

// ============ PHASE Q: q = Wq h_new + bq (vb in [0,512)) ============
template<bool F32>
__device__ void phaseQ(const P& p, int t, int vb, Smem& sm)
{
  const int b=vb>>2, qt=vb&3, l=threadIdx.x, d=qt*64+l;
  float* hs = sm.ls.hs;
  for (int i=l;i<HD_;i+=64) hs[i]=g_hh[(t+1)&1][b*HD_+i];
  __syncthreads();
  float acc = ld1<F32>(p.bq,d);
  #pragma unroll 4
  for (int kk=0;kk<HD_/8;kk++){
    float w[8]; ld8<F32>(p.Wq,(size_t)d*HD_+kk*8,w);
    #pragma unroll
    for (int j=0;j<8;j++) acc=fmaf(hs[kk*8+j],w[j],acc);
  }
  g_q[b*HD_+d]=acc;
  __syncthreads();
}

// ============ PHASE B: logits + per-segment top-3 (vb in [0,1024)) ============
// vb -> (b = vb>>3, seg = vb&7); round-6 engine: linear global_load_lds,
// double-buffered 16KB tiles, counted vmcnt(16), rotated-slot LDS reads.
template<bool F32>
__device__ void phaseB(const P& p, int t, int vb, Smem& sm)
{
  const int b=vb>>3, seg=vb&7, l=threadIdx.x;
  float* qs = sm.lg.qs;
  for (int i=l;i<HD_;i+=64) qs[i]=g_q[b*HD_+i];
  __syncthreads();

  float v0=-3.4e38f,v1=-3.4e38f,v2=-3.4e38f; int i0=-1,i1=-1,i2=-1;
  const int rowglob0 = seg*SEGROWS_;

  if constexpr (!F32){
    uint4 (*buf)[1024] = sm.lg.buf;
    const u16* encb = (const u16*)p.enc + ((size_t)b*N_+(size_t)seg*SEGROWS_)*HD_;
    u16* outb = (u16*)p.out + (size_t)t*B_*N_ + (size_t)b*N_ + (size_t)seg*SEGROWS_;
    const int r  = l & 31;
    const int up = l >> 5;

    #define STAGE(T) do{                                                      \
      const u16* s0 = encb + (size_t)(T)*32*HD_ + l*8;                        \
      _Pragma("unroll")                                                       \
      for (int i_=0;i_<16;i_++)                                               \
        __builtin_amdgcn_global_load_lds(GLBP(s0 + i_*512),                   \
                                         LDSP(&buf[(T)&1][i_*64]), 16, 0, 0); \
    }while(0)
    #define COMP(T) do{                                                       \
      const uint4* rowp = &buf[(T)&1][r*32];                                  \
      float acc_ = 0.f;                                                       \
      _Pragma("unroll")                                                       \
      for (int j_=0;j_<16;j_++){                                              \
        const int s_ = ((j_ + r) & 15) + up*16;                               \
        uint4 u_ = rowp[s_];                                                  \
        const float* qk_ = &qs[s_*8];                                         \
        acc_ = fmaf(lo2f(u_.x), qk_[0], acc_);                                \
        acc_ = fmaf(hi2f(u_.x), qk_[1], acc_);                                \
        acc_ = fmaf(lo2f(u_.y), qk_[2], acc_);                                \
        acc_ = fmaf(hi2f(u_.y), qk_[3], acc_);                                \
        acc_ = fmaf(lo2f(u_.z), qk_[4], acc_);                                \
        acc_ = fmaf(hi2f(u_.z), qk_[5], acc_);                                \
        acc_ = fmaf(lo2f(u_.w), qk_[6], acc_);                                \
        acc_ = fmaf(hi2f(u_.w), qk_[7], acc_);                                \
      }                                                                       \
      acc_ += __shfl_xor(acc_, 32, 64);                                       \
      if (l < 32){                                                            \
        t3ins(acc_, rowglob0 + (T)*32 + r, v0,i0,v1,i1,v2,i2);                \
        outb[(T)*32 + r] = f2bf(acc_);                                        \
      }                                                                       \
    }while(0)

    STAGE(0);
    #pragma unroll 1
    for (int T=0;T<31;T++){
      STAGE(T+1);
      asm volatile("s_waitcnt vmcnt(16)" ::: "memory");
      COMP(T);
    }
    asm volatile("s_waitcnt vmcnt(0)" ::: "memory");
    COMP(31);
    #undef STAGE
    #undef COMP
  } else {
    const float* encb = (const float*)p.enc + ((size_t)b*N_+(size_t)seg*SEGROWS_)*HD_;
    float* outb = (float*)p.out + (size_t)t*B_*N_ + (size_t)b*N_ + (size_t)seg*SEGROWS_;
    for (int row=l; row<SEGROWS_; row+=64){
      const float4* rp = (const float4*)(encb + (size_t)row*HD_);
      float acc = 0.f;
      #pragma unroll 8
      for (int k=0;k<64;k++){
        float4 v = rp[k];
        const float* qk = &qs[k*4];
        acc = fmaf(v.x, qk[0], acc);
        acc = fmaf(v.y, qk[1], acc);
        acc = fmaf(v.z, qk[2], acc);
        acc = fmaf(v.w, qk[3], acc);
      }
      t3ins(acc, rowglob0 + row, v0,i0,v1,i1,v2,i2);
      outb[row] = acc;
    }
  }

  // wave butterfly top-3 merge
  #pragma unroll
  for (int d=1; d<64; d<<=1){
    float w0=__shfl_xor(v0,d,64), w1=__shfl_xor(v1,d,64), w2=__shfl_xor(v2,d,64);
    int   j0=__shfl_xor(i0,d,64), j1=__shfl_xor(i1,d,64), j2=__shfl_xor(i2,d,64);
    t3ins(w0,j0, v0,i0,v1,i1,v2,i2);
    t3ins(w1,j1, v0,i0,v1,i1,v2,i2);
    t3ins(w2,j2, v0,i0,v1,i1,v2,i2);
  }
  if (l==0){
    float* pv = g_pval + (b*SEGS_+seg)*3;
    int*   pi = g_pidx + (b*SEGS_+seg)*3;
    pv[0]=v0; pv[1]=v1; pv[2]=v2;
    pi[0]=i0; pi[1]=i1; pi[2]=i2;
  }
  __syncthreads();   // LDS reuse across grid-stride iterations
}

// ============ PHASE F: final idx merge (vb in [0,128)) ============
template<bool F32>
__device__ void phaseF(const P& p, int vb)
{
  if (threadIdx.x==0){
    float v0=-3.4e38f,v1=-3.4e38f,v2=-3.4e38f; int i0=-1,i1=-1,i2=-1;
    const float* pv = g_pval + vb*SEGS_*3;
    const int*   pi = g_pidx + vb*SEGS_*3;
    for (int s=0;s<SEGS_*3;s++) t3ins(pv[s],pi[s],v0,i0,v1,i1,v2,i2);
    const size_t ib = (size_t)T_*B_*N_ + (size_t)(T_-1)*B_*3 + (size_t)vb*3;
    st1<F32>(p.out, ib+0, (float)i0);
    st1<F32>(p.out, ib+1, (float)i1);
    st1<F32>(p.out, ib+2, (float)i2);
  }
}

// ============ cooperative fused kernel ============
template<bool F32>
__device__ void coop_run(const P& p, int nb)
{
  __shared__ Smem sm;
  cg::grid_group grid = cg::this_grid();
  for (int t=0;t<T_;t++){
    for (int vb=blockIdx.x; vb<512; vb+=nb)       phaseA<F32>(p,t,vb,sm);
    grid.sync();
    for (int vb=blockIdx.x; vb<512; vb+=nb)       phaseQ<F32>(p,t,vb,sm);
    grid.sync();
    for (int vb=blockIdx.x; vb<B_*SEGS_; vb+=nb)  phaseB<F32>(p,t,vb,sm);
    grid.sync();
  }
  for (int vb=blockIdx.x; vb<B_; vb+=nb)          phaseF<F32>(p,vb);
}

__global__ __launch_bounds__(64) void k_all(P p, int nb)
{
  if (g_isf32) coop_run<true >(p,nb);
  else         coop_run<false>(p,nb);
}

// ============ non-cooperative fallback (same phase bodies) ============
__global__ __launch_bounds__(64) void k_pA(P p, int t)
{ __shared__ Smem sm;
  if (g_isf32) phaseA<true >(p,t,blockIdx.x,sm); else phaseA<false>(p,t,blockIdx.x,sm); }
__global__ __launch_bounds__(64) void k_pQ(P p, int t)
{ __shared__ Smem sm;
  if (g_isf32) phaseQ<true >(p,t,blockIdx.x,sm); else phaseQ<false>(p,t,blockIdx.x,sm); }
__global__ __launch_bounds__(64) void k_pB(P p, int t)
{ __shared__ Smem sm;
  if (g_isf32) phaseB<true >(p,t,blockIdx.x,sm); else phaseB<false>(p,t,blockIdx.x,sm); }
__global__ __launch_bounds__(64) void k_pF(P p)
{ if (g_isf32) phaseF<true >(p,blockIdx.x); else phaseF<false>(p,blockIdx.x); }

extern "C" void kernel_launch(void* const* d_in, const int* in_sizes, int n_in,
                              void* d_out, int out_size, void* d_ws, size_t ws_size,
                              hipStream_t stream)
{
  (void)in_sizes; (void)n_in; (void)out_size; (void)d_ws; (void)ws_size;
  P p;
  p.enc = d_in[0];
  p.h0  = d_in[1];
  p.c0  = d_in[2];
  // d_in[3] end_node_embed: unused in prediction mode
  p.x0  = d_in[4];
  p.Wih = d_in[5];
  p.bih = d_in[6];
  p.Whh = d_in[7];
  p.bhh = d_in[8];
  p.Wq  = d_in[9];
  p.bq  = d_in[10];
  // d_in[11] max_steps == 10 (fixed by setup_inputs)
  p.out = d_out;

  k_probe<<<dim3(1),dim3(64),0,stream>>>(p.enc);

  int occ = 0;
  hipError_t oe = hipOccupancyMaxActiveBlocksPerMultiprocessor(&occ, k_all, 64, 0);
  bool done = false;
  if (oe == hipSuccess && occ > 0){
    int nb = occ * 256;                 // 256 CUs
    if (nb > B_*SEGS_) nb = B_*SEGS_;   // no more than total work items
    if (nb >= 64){
      void* args[] = { (void*)&p, (void*)&nb };
      hipError_t le = hipLaunchCooperativeKernel((void*)k_all, dim3(nb), dim3(64),
                                                 args, 0, stream);
      done = (le == hipSuccess);
    }
  }

  if (!done){
    for (int t=0;t<T_;t++){
      k_pA<<<dim3(512),      dim3(64),0,stream>>>(p, t);
      k_pQ<<<dim3(512),      dim3(64),0,stream>>>(p, t);
      k_pB<<<dim3(B_*SEGS_), dim3(64),0,stream>>>(p, t);
    }
    k_pF<<<dim3(B_),dim3(64),0,stream>>>(p);
  }
}

// Round 9
// 4320.174 us; speedup vs baseline: 1.3681x; 1.3681x over previous
//
#include <hip/hip_runtime.h>

typedef unsigned short u16;
typedef unsigned int   u32;

#define B_    128
#define N_    8192
#define HD_   256
#define X_    768          // 3*HD
#define T_    10
#define SEGS_ 16
#define SEGROWS_ 512       // N_/SEGS_

// ---- persistent per-call state in device globals ----
__device__ float g_h[B_*HD_];
__device__ float g_c[B_*HD_];
__device__ float g_q[B_*HD_];
__device__ float g_pval[B_*SEGS_*3];
__device__ int   g_pidx[B_*SEGS_*3];
__device__ int   g_isf32;

struct P {
  const void *enc, *h0, *c0, *x0, *Wih, *bih, *Whh, *bhh, *Wq, *bq;
  void* out;
};

// clang-native vectors: no constructors -> loadable through AS(1) pointers.
typedef u32   u32x4 __attribute__((ext_vector_type(4)));
typedef float f32x4 __attribute__((ext_vector_type(4)));
// explicit global-address-space pointer: guarantees global_load_* (vmcnt-only),
// never flat_load (flat counts in BOTH vmcnt and lgkmcnt and gets drained by
// the shfl's lgkmcnt waits — the round-3/4 failure mode).
typedef const __attribute__((address_space(1))) u32x4* gu4;
typedef const __attribute__((address_space(1))) f32x4* gf4;

__device__ __forceinline__ float bf2f(u16 u){ return __uint_as_float(((u32)u)<<16); }
__device__ __forceinline__ float lo2f(u32 w){ return __uint_as_float(w<<16); }
__device__ __forceinline__ float hi2f(u32 w){ return __uint_as_float(w & 0xffff0000u); }
__device__ __forceinline__ u16 f2bf(float f){
  u32 u = __float_as_uint(f);
  u32 r = u + 0x7fffu + ((u>>16)&1u);   // RNE
  return (u16)(r>>16);
}

template<bool F32>
__device__ __forceinline__ float ld1(const void* p, size_t i){
  if constexpr (F32) return ((const float*)p)[i];
  else               return bf2f(((const u16*)p)[i]);
}

template<bool F32>
__device__ __forceinline__ void st1(void* p, size_t i, float v){
  if constexpr (F32) ((float*)p)[i] = v;
  else               ((u16*)p)[i]   = f2bf(v);
}

template<bool F32>
__device__ __forceinline__ void ld8(const void* p, size_t i, float* o){
  if constexpr (F32){
    const float4* q = (const float4*)((const float*)p + i);
    float4 a = q[0], b = q[1];
    o[0]=a.x; o[1]=a.y; o[2]=a.z; o[3]=a.w;
    o[4]=b.x; o[5]=b.y; o[6]=b.z; o[7]=b.w;
  } else {
    uint4 u = *(const uint4*)((const u16*)p + i);
    o[0]=lo2f(u.x); o[1]=hi2f(u.x); o[2]=lo2f(u.y); o[3]=hi2f(u.y);
    o[4]=lo2f(u.z); o[5]=hi2f(u.z); o[6]=lo2f(u.w); o[7]=hi2f(u.w);
  }
}

// top-3 insert, jax.lax.top_k tie-break (equal value -> lower index first)
__device__ __forceinline__ void t3ins(float v,int i,
    float&v0,int&i0,float&v1,int&i1,float&v2,int&i2){
  if (v>v0 || (v==v0 && i<i0)) { v2=v1;i2=i1; v1=v0;i1=i0; v0=v;i0=i; }
  else if (v>v1 || (v==v1 && i<i1)) { v2=v1;i2=i1; v1=v;i1=i; }
  else if (v>v2 || (v==v2 && i<i2)) { v2=v;i2=i; }
}

// ---- dtype probe ----
__global__ void k_probe(const void* enc){
  const int lane = threadIdx.x;           // 64 threads
  const u16 u = ((const u16*)enc)[lane*2];
  const float a = fabsf(bf2f(u));
  const bool inr = (a >= 0.0009765625f) && (a <= 1024.0f);
  unsigned long long m = __ballot(inr ? 1 : 0);
  if (lane==0) g_isf32 = (__popcll(m) < 32) ? 1 : 0;
}

// ---- K1: merge prev partials -> idx output + gather x, LSTM, query ----
template<bool F32>
__device__ void lstm_b(const P& p, int t, int b, float* xs, float* hs, float* hn)
{
  const int d = threadIdx.x;
  __shared__ int idx3[3];

  float cd;
  if (t == 0){
    for (int i=d;i<X_;i+=256) xs[i] = ld1<F32>(p.x0, (size_t)b*X_+i);
    hs[d] = ld1<F32>(p.h0, (size_t)b*HD_+d);
    cd    = ld1<F32>(p.c0, (size_t)b*HD_+d);
  } else {
    if (d==0){
      float v0=-3.4e38f,v1=-3.4e38f,v2=-3.4e38f; int i0=-1,i1=-1,i2=-1;
      const float* pv = g_pval + b*SEGS_*3;
      const int*   pi = g_pidx + b*SEGS_*3;
      for (int s=0;s<SEGS_*3;s++) t3ins(pv[s],pi[s],v0,i0,v1,i1,v2,i2);
      idx3[0]=i0; idx3[1]=i1; idx3[2]=i2;
      const size_t ib = (size_t)T_*B_*N_ + (size_t)(t-1)*B_*3 + (size_t)b*3;
      st1<F32>(p.out, ib+0, (float)i0);
      st1<F32>(p.out, ib+1, (float)i1);
      st1<F32>(p.out, ib+2, (float)i2);
    }
    __syncthreads();
    #pragma unroll
    for (int j=0;j<3;j++){
      int jj = idx3[j]; jj = jj<0 ? 0 : (jj>N_-1 ? N_-1 : jj);   // crash guard
      xs[j*HD_+d] = ld1<F32>(p.enc, ((size_t)b*N_ + jj)*HD_ + d);
    }
    hs[d] = g_h[b*HD_+d];
    cd    = g_c[b*HD_+d];
  }
  __syncthreads();

  float g4[4];
  #pragma unroll
  for (int gi=0;gi<4;gi++){
    const int row = gi*HD_ + d;
    float acc = ld1<F32>(p.bih,row) + ld1<F32>(p.bhh,row);
    #pragma unroll 4
    for (int kk=0;kk<X_/8;kk++){
      float w[8]; ld8<F32>(p.Wih, (size_t)row*X_ + kk*8, w);
      #pragma unroll
      for (int j=0;j<8;j++) acc = fmaf(xs[kk*8+j], w[j], acc);
    }
    #pragma unroll 4
    for (int kk=0;kk<HD_/8;kk++){
      float w[8]; ld8<F32>(p.Whh, (size_t)row*HD_ + kk*8, w);
      #pragma unroll
      for (int j=0;j<8;j++) acc = fmaf(hs[kk*8+j], w[j], acc);
    }
    g4[gi]=acc;
  }
  const float sig_i = 1.f/(1.f+expf(-g4[0]));
  const float sig_f = 1.f/(1.f+expf(-g4[1]));
  const float tan_g = tanhf(g4[2]);
  const float sig_o = 1.f/(1.f+expf(-g4[3]));
  const float cn = sig_f*cd + sig_i*tan_g;
  const float hv = sig_o*tanhf(cn);
  g_c[b*HD_+d]=cn; g_h[b*HD_+d]=hv; hn[d]=hv;
  __syncthreads();

  float acc = ld1<F32>(p.bq,d);
  #pragma unroll 4
  for (int kk=0;kk<HD_/8;kk++){
    float w[8]; ld8<F32>(p.Wq, (size_t)d*HD_ + kk*8, w);
    #pragma unroll
    for (int j=0;j<8;j++) acc = fmaf(hn[kk*8+j], w[j], acc);
  }
  g_q[b*HD_+d]=acc;
}

__global__ __launch_bounds__(256) void k_lstm(P p, int t)
{
  __shared__ float xs[X_], hs[HD_], hn[HD_];   // shared by both instantiations
  if (g_isf32) lstm_b<true >(p, t, blockIdx.x, xs, hs, hn);
  else         lstm_b<false>(p, t, blockIdx.x, xs, hs, hn);
}

// ---- K2: logits. 256-thread blocks (4 waves), register-load engine:
// coalesced 1KB/instr global_load_dwordx4 (AS(1) ext-vector), 8-deep static
// prefetch pipeline (8KB in flight/wave), 32-lanes-per-row shfl reduce
// (lgkmcnt-only, does NOT drain global loads), logits to LDS, coalesced flush.
template<bool F32>
__device__ void logits_b(const P& p, int t, int b, int seg,
                         float* qs, float* lbuf, float (*sv)[3], int (*si)[3])
{
  const int tid  = threadIdx.x;
  const int wave = tid>>6;
  const int l    = tid&63;
  const int kl   = l&31;
  const int half = l>>5;

  for (int i=tid;i<HD_;i+=256) qs[i] = g_q[b*HD_+i];
  __syncthreads();

  float v0=-3.4e38f,v1=-3.4e38f,v2=-3.4e38f; int i0=-1,i1=-1,i2=-1;
  const int rowg0 = seg*SEGROWS_;

  if constexpr (!F32){
    // lane's fixed q fragment (cols kl*8 .. kl*8+7)
    float qv[8];
    #pragma unroll
    for (int j=0;j<8;j++) qv[j] = qs[kl*8+j];

    const u16* encb = (const u16*)p.enc + ((size_t)b*N_ + (size_t)seg*SEGROWS_)*HD_;
    // wave w owns rows [w*128, w*128+128); per iteration: 2 rows (1KB coalesced)
    const int wr0 = wave*128;
    gu4 gbase = (gu4)(encb + ((size_t)(wr0 + half))*HD_ + kl*8);
    // u32x4-stride between iterations: 2 rows * 256 elems / 8 = 64

    u32x4 pf[8];
    #pragma unroll
    for (int ii=0;ii<8;ii++) pf[ii] = gbase[(size_t)ii*64];

    #pragma unroll 1
    for (int ito=0; ito<8; ++ito){
      #pragma unroll
      for (int ii=0;ii<8;ii++){
        const int it = ito*8 + ii;
        u32x4 u = pf[ii];
        if (ito < 7) pf[ii] = gbase[(size_t)(it+8)*64];
        float acc =       qv[0]*lo2f(u.x);
        acc = fmaf(qv[1], hi2f(u.x), acc);
        acc = fmaf(qv[2], lo2f(u.y), acc);
        acc = fmaf(qv[3], hi2f(u.y), acc);
        acc = fmaf(qv[4], lo2f(u.z), acc);
        acc = fmaf(qv[5], hi2f(u.z), acc);
        acc = fmaf(qv[6], lo2f(u.w), acc);
        acc = fmaf(qv[7], hi2f(u.w), acc);
        acc += __shfl_xor(acc, 1, 64);
        acc += __shfl_xor(acc, 2, 64);
        acc += __shfl_xor(acc, 4, 64);
        acc += __shfl_xor(acc, 8, 64);
        acc += __shfl_xor(acc, 16, 64);    // all lanes of the half hold row sum
        const int row = wr0 + 2*it + half;
        if (kl==0) lbuf[row] = acc;
        t3ins(acc, rowg0 + row, v0,i0,v1,i1,v2,i2);  // identical across half
      }
    }
  } else {
    // f32 fallback: lane-owns-row streaming (correctness-first)
    const float* encb = (const float*)p.enc + ((size_t)b*N_ + (size_t)seg*SEGROWS_)*HD_;
    for (int row=tid; row<SEGROWS_; row+=256){
      gf4 rp = (gf4)(encb + (size_t)row*HD_);
      float acc = 0.f;
      #pragma unroll 8
      for (int k=0;k<64;k++){
        f32x4 v = rp[k];
        const float* qk = &qs[k*4];
        acc = fmaf(v.x, qk[0], acc);
        acc = fmaf(v.y, qk[1], acc);
        acc = fmaf(v.z, qk[2], acc);
        acc = fmaf(v.w, qk[3], acc);
      }
      lbuf[row] = acc;
      t3ins(acc, rowg0 + row, v0,i0,v1,i1,v2,i2);
    }
  }

  // keep one copy per disjoint row-set, then single exchange merge
  if constexpr (!F32){
    if (kl!=0){ v0=v1=v2=-3.4e38f; i0=i1=i2=-1; }
    float w0=__shfl_xor(v0,32,64), w1=__shfl_xor(v1,32,64), w2=__shfl_xor(v2,32,64);
    int   j0=__shfl_xor(i0,32,64), j1=__shfl_xor(i1,32,64), j2=__shfl_xor(i2,32,64);
    t3ins(w0,j0, v0,i0,v1,i1,v2,i2);
    t3ins(w1,j1, v0,i0,v1,i1,v2,i2);
    t3ins(w2,j2, v0,i0,v1,i1,v2,i2);
  } else {
    #pragma unroll
    for (int d=1; d<64; d<<=1){
      float w0=__shfl_xor(v0,d,64), w1=__shfl_xor(v1,d,64), w2=__shfl_xor(v2,d,64);
      int   j0=__shfl_xor(i0,d,64), j1=__shfl_xor(i1,d,64), j2=__shfl_xor(i2,d,64);
      t3ins(w0,j0, v0,i0,v1,i1,v2,i2);
      t3ins(w1,j1, v0,i0,v1,i1,v2,i2);
      t3ins(w2,j2, v0,i0,v1,i1,v2,i2);
    }
  }
  if (l==0){
    sv[wave][0]=v0; sv[wave][1]=v1; sv[wave][2]=v2;
    si[wave][0]=i0; si[wave][1]=i1; si[wave][2]=i2;
  }
  __syncthreads();

  if (tid==0){
    float w0=-3.4e38f,w1=-3.4e38f,w2=-3.4e38f; int j0=-1,j1=-1,j2=-1;
    for (int s=0;s<4;s++)
      for (int k=0;k<3;k++)
        t3ins(sv[s][k],si[s][k],w0,j0,w1,j1,w2,j2);
    float* pv = g_pval + (b*SEGS_+seg)*3;
    int*   pi = g_pidx + (b*SEGS_+seg)*3;
    pv[0]=w0; pv[1]=w1; pv[2]=w2;
    pi[0]=j0; pi[1]=j1; pi[2]=j2;
  }

  // coalesced logits flush
  const size_t obase = (size_t)t*B_*N_ + (size_t)b*N_ + (size_t)seg*SEGROWS_;
  if constexpr (!F32){
    u32* o4 = (u32*)((u16*)p.out + obase);
    o4[tid] = (u32)f2bf(lbuf[2*tid]) | ((u32)f2bf(lbuf[2*tid+1])<<16);
  } else {
    float2* o2 = (float2*)((float*)p.out + obase);
    o2[tid] = make_float2(lbuf[2*tid], lbuf[2*tid+1]);
  }
}

__global__ __launch_bounds__(256) void k_logits(P p, int t)
{
  __shared__ float qs[HD_];
  __shared__ float lbuf[SEGROWS_];
  __shared__ float sv[4][3];
  __shared__ int   si[4][3];
  const int b   = blockIdx.x >> 4;
  const int seg = blockIdx.x & 15;
  if (g_isf32) logits_b<true >(p, t, b, seg, qs, lbuf, sv, si);
  else         logits_b<false>(p, t, b, seg, qs, lbuf, sv, si);
}

// ---- K3: final merge for the last step's indices ----
template<bool F32>
__device__ void final_b(const P& p, int b)
{
  if (threadIdx.x==0){
    float v0=-3.4e38f,v1=-3.4e38f,v2=-3.4e38f; int i0=-1,i1=-1,i2=-1;
    const float* pv = g_pval + b*SEGS_*3;
    const int*   pi = g_pidx + b*SEGS_*3;
    for (int s=0;s<SEGS_*3;s++) t3ins(pv[s],pi[s],v0,i0,v1,i1,v2,i2);
    const size_t ib = (size_t)T_*B_*N_ + (size_t)(T_-1)*B_*3 + (size_t)b*3;
    st1<F32>(p.out, ib+0, (float)i0);
    st1<F32>(p.out, ib+1, (float)i1);
    st1<F32>(p.out, ib+2, (float)i2);
  }
}

__global__ void k_final(P p)
{
  if (g_isf32) final_b<true >(p, blockIdx.x);
  else         final_b<false>(p, blockIdx.x);
}

extern "C" void kernel_launch(void* const* d_in, const int* in_sizes, int n_in,
                              void* d_out, int out_size, void* d_ws, size_t ws_size,
                              hipStream_t stream)
{
  (void)in_sizes; (void)n_in; (void)out_size; (void)d_ws; (void)ws_size;
  P p;
  p.enc = d_in[0];
  p.h0  = d_in[1];
  p.c0  = d_in[2];
  // d_in[3] end_node_embed: unused in prediction mode
  p.x0  = d_in[4];
  p.Wih = d_in[5];
  p.bih = d_in[6];
  p.Whh = d_in[7];
  p.bhh = d_in[8];
  p.Wq  = d_in[9];
  p.bq  = d_in[10];
  // d_in[11] max_steps == 10 (fixed by setup_inputs)
  p.out = d_out;

  k_probe<<<dim3(1),dim3(64),0,stream>>>(p.enc);

  for (int t=0;t<T_;t++){
    k_lstm  <<<dim3(B_),        dim3(256),0,stream>>>(p, t);
    k_logits<<<dim3(B_*SEGS_),  dim3(256),0,stream>>>(p, t);
  }
  k_final<<<dim3(B_),dim3(64),0,stream>>>(p);
}

// Round 10
// 4301.893 us; speedup vs baseline: 1.3739x; 1.0042x over previous
//
#include <hip/hip_runtime.h>

typedef unsigned short u16;
typedef unsigned int   u32;

#define B_    128
#define N_    8192
#define HD_   256
#define X_    768          // 3*HD
#define T_    10
#define SEGS_ 16
#define SEGROWS_ 512       // N_/SEGS_

// ---- persistent per-call state in device globals ----
__device__ float g_h[B_*HD_];
__device__ float g_c[B_*HD_];
__device__ float g_q[B_*HD_];
__device__ float g_pval[B_*SEGS_*3];
__device__ int   g_pidx[B_*SEGS_*3];
__device__ int   g_isf32;

struct P {
  const void *enc, *h0, *c0, *x0, *Wih, *bih, *Whh, *bhh, *Wq, *bq;
  void* out;
};

// clang-native vectors: no constructors -> loadable through AS(1) pointers.
typedef u32   u32x4 __attribute__((ext_vector_type(4)));
typedef float f32x4 __attribute__((ext_vector_type(4)));
// explicit global-address-space pointer: guarantees global_load_* (vmcnt-only),
// never flat_load (flat counts in BOTH vmcnt and lgkmcnt and gets drained by
// the shfl's lgkmcnt waits — the round-3/4 failure mode).
typedef const __attribute__((address_space(1))) u32x4* gu4;
typedef const __attribute__((address_space(1))) f32x4* gf4;

__device__ __forceinline__ float bf2f(u16 u){ return __uint_as_float(((u32)u)<<16); }
__device__ __forceinline__ float lo2f(u32 w){ return __uint_as_float(w<<16); }
__device__ __forceinline__ float hi2f(u32 w){ return __uint_as_float(w & 0xffff0000u); }
__device__ __forceinline__ u16 f2bf(float f){
  u32 u = __float_as_uint(f);
  u32 r = u + 0x7fffu + ((u>>16)&1u);   // RNE
  return (u16)(r>>16);
}

template<bool F32>
__device__ __forceinline__ float ld1(const void* p, size_t i){
  if constexpr (F32) return ((const float*)p)[i];
  else               return bf2f(((const u16*)p)[i]);
}

template<bool F32>
__device__ __forceinline__ void st1(void* p, size_t i, float v){
  if constexpr (F32) ((float*)p)[i] = v;
  else               ((u16*)p)[i]   = f2bf(v);
}

template<bool F32>
__device__ __forceinline__ void ld8(const void* p, size_t i, float* o){
  if constexpr (F32){
    const float4* q = (const float4*)((const float*)p + i);
    float4 a = q[0], b = q[1];
    o[0]=a.x; o[1]=a.y; o[2]=a.z; o[3]=a.w;
    o[4]=b.x; o[5]=b.y; o[6]=b.z; o[7]=b.w;
  } else {
    uint4 u = *(const uint4*)((const u16*)p + i);
    o[0]=lo2f(u.x); o[1]=hi2f(u.x); o[2]=lo2f(u.y); o[3]=hi2f(u.y);
    o[4]=lo2f(u.z); o[5]=hi2f(u.z); o[6]=lo2f(u.w); o[7]=hi2f(u.w);
  }
}

// top-3 insert, jax.lax.top_k tie-break (equal value -> lower index first)
__device__ __forceinline__ void t3ins(float v,int i,
    float&v0,int&i0,float&v1,int&i1,float&v2,int&i2){
  if (v>v0 || (v==v0 && i<i0)) { v2=v1;i2=i1; v1=v0;i1=i0; v0=v;i0=i; }
  else if (v>v1 || (v==v1 && i<i1)) { v2=v1;i2=i1; v1=v;i1=i; }
  else if (v>v2 || (v==v2 && i<i2)) { v2=v;i2=i; }
}

// ---- dtype probe ----
__global__ void k_probe(const void* enc){
  const int lane = threadIdx.x;           // 64 threads
  const u16 u = ((const u16*)enc)[lane*2];
  const float a = fabsf(bf2f(u));
  const bool inr = (a >= 0.0009765625f) && (a <= 1024.0f);
  unsigned long long m = __ballot(inr ? 1 : 0);
  if (lane==0) g_isf32 = (__popcll(m) < 32) ? 1 : 0;
}

// ---- K1: merge prev partials -> idx output + gather x, LSTM, query ----
template<bool F32>
__device__ void lstm_b(const P& p, int t, int b, float* xs, float* hs, float* hn)
{
  const int d = threadIdx.x;
  __shared__ int idx3[3];

  float cd;
  if (t == 0){
    for (int i=d;i<X_;i+=256) xs[i] = ld1<F32>(p.x0, (size_t)b*X_+i);
    hs[d] = ld1<F32>(p.h0, (size_t)b*HD_+d);
    cd    = ld1<F32>(p.c0, (size_t)b*HD_+d);
  } else {
    if (d==0){
      float v0=-3.4e38f,v1=-3.4e38f,v2=-3.4e38f; int i0=-1,i1=-1,i2=-1;
      const float* pv = g_pval + b*SEGS_*3;
      const int*   pi = g_pidx + b*SEGS_*3;
      for (int s=0;s<SEGS_*3;s++) t3ins(pv[s],pi[s],v0,i0,v1,i1,v2,i2);
      idx3[0]=i0; idx3[1]=i1; idx3[2]=i2;
      const size_t ib = (size_t)T_*B_*N_ + (size_t)(t-1)*B_*3 + (size_t)b*3;
      st1<F32>(p.out, ib+0, (float)i0);
      st1<F32>(p.out, ib+1, (float)i1);
      st1<F32>(p.out, ib+2, (float)i2);
    }
    __syncthreads();
    #pragma unroll
    for (int j=0;j<3;j++){
      int jj = idx3[j]; jj = jj<0 ? 0 : (jj>N_-1 ? N_-1 : jj);   // crash guard
      xs[j*HD_+d] = ld1<F32>(p.enc, ((size_t)b*N_ + jj)*HD_ + d);
    }
    hs[d] = g_h[b*HD_+d];
    cd    = g_c[b*HD_+d];
  }
  __syncthreads();

  float g4[4];
  #pragma unroll
  for (int gi=0;gi<4;gi++){
    const int row = gi*HD_ + d;
    float acc = ld1<F32>(p.bih,row) + ld1<F32>(p.bhh,row);
    #pragma unroll 4
    for (int kk=0;kk<X_/8;kk++){
      float w[8]; ld8<F32>(p.Wih, (size_t)row*X_ + kk*8, w);
      #pragma unroll
      for (int j=0;j<8;j++) acc = fmaf(xs[kk*8+j], w[j], acc);
    }
    #pragma unroll 4
    for (int kk=0;kk<HD_/8;kk++){
      float w[8]; ld8<F32>(p.Whh, (size_t)row*HD_ + kk*8, w);
      #pragma unroll
      for (int j=0;j<8;j++) acc = fmaf(hs[kk*8+j], w[j], acc);
    }
    g4[gi]=acc;
  }
  const float sig_i = 1.f/(1.f+expf(-g4[0]));
  const float sig_f = 1.f/(1.f+expf(-g4[1]));
  const float tan_g = tanhf(g4[2]);
  const float sig_o = 1.f/(1.f+expf(-g4[3]));
  const float cn = sig_f*cd + sig_i*tan_g;
  const float hv = sig_o*tanhf(cn);
  g_c[b*HD_+d]=cn; g_h[b*HD_+d]=hv; hn[d]=hv;
  __syncthreads();

  float acc = ld1<F32>(p.bq,d);
  #pragma unroll 4
  for (int kk=0;kk<HD_/8;kk++){
    float w[8]; ld8<F32>(p.Wq, (size_t)d*HD_ + kk*8, w);
    #pragma unroll
    for (int j=0;j<8;j++) acc = fmaf(hn[kk*8+j], w[j], acc);
  }
  g_q[b*HD_+d]=acc;
}

__global__ __launch_bounds__(256) void k_lstm(P p, int t)
{
  __shared__ float xs[X_], hs[HD_], hn[HD_];   // shared by both instantiations
  if (g_isf32) lstm_b<true >(p, t, blockIdx.x, xs, hs, hn);
  else         lstm_b<false>(p, t, blockIdx.x, xs, hs, hn);
}

// ---- K2: logits — round-9 register engine + CAMPING-BUSTER phase rotation.
// Concurrent blocks previously all read addresses congruent mod 256KB in
// lockstep (power-of-2 channel/set camping). Each (block,wave) now walks its
// 64 row-pair iterations in a rotated order, de-phasing concurrent addresses
// across ~64KB. Top-3 insert and lbuf writes are order-independent.
template<bool F32>
__device__ void logits_b(const P& p, int t, int b, int seg,
                         float* qs, float* lbuf, float (*sv)[3], int (*si)[3])
{
  const int tid  = threadIdx.x;
  const int wave = tid>>6;
  const int l    = tid&63;
  const int kl   = l&31;
  const int half = l>>5;

  for (int i=tid;i<HD_;i+=256) qs[i] = g_q[b*HD_+i];
  __syncthreads();

  float v0=-3.4e38f,v1=-3.4e38f,v2=-3.4e38f; int i0=-1,i1=-1,i2=-1;
  const int rowg0 = seg*SEGROWS_;

  if constexpr (!F32){
    // lane's fixed q fragment (cols kl*8 .. kl*8+7)
    float qv[8];
    #pragma unroll
    for (int j=0;j<8;j++) qv[j] = qs[kl*8+j];

    const u16* encb = (const u16*)p.enc + ((size_t)b*N_ + (size_t)seg*SEGROWS_)*HD_;
    // wave w owns rows [w*128, w*128+128); per iteration: 2 rows (1KB coalesced)
    const int wr0 = wave*128;
    gu4 gbase = (gu4)(encb + ((size_t)(wr0 + half))*HD_ + kl*8);
    // u32x4-stride between iterations: 2 rows * 256 elems / 8 = 64

    // per-(block,wave) iteration-order rotation — the de-camping lever
    const int ph = ((int)blockIdx.x * 37 + wave * 16) & 63;

    u32x4 pf[8];
    #pragma unroll
    for (int ii=0;ii<8;ii++) pf[ii] = gbase[(size_t)(((ii+ph)&63))*64];

    #pragma unroll 1
    for (int ito=0; ito<8; ++ito){
      #pragma unroll
      for (int ii=0;ii<8;ii++){
        const int s = ito*8 + ii;
        u32x4 u = pf[ii];
        if (ito < 7) pf[ii] = gbase[(size_t)(((s+8+ph)&63))*64];
        float acc =       qv[0]*lo2f(u.x);
        acc = fmaf(qv[1], hi2f(u.x), acc);
        acc = fmaf(qv[2], lo2f(u.y), acc);
        acc = fmaf(qv[3], hi2f(u.y), acc);
        acc = fmaf(qv[4], lo2f(u.z), acc);
        acc = fmaf(qv[5], hi2f(u.z), acc);
        acc = fmaf(qv[6], lo2f(u.w), acc);
        acc = fmaf(qv[7], hi2f(u.w), acc);
        acc += __shfl_xor(acc, 1, 64);
        acc += __shfl_xor(acc, 2, 64);
        acc += __shfl_xor(acc, 4, 64);
        acc += __shfl_xor(acc, 8, 64);
        acc += __shfl_xor(acc, 16, 64);    // all lanes of the half hold row sum
        const int itp = (s + ph) & 63;
        const int row = wr0 + 2*itp + half;
        if (kl==0) lbuf[row] = acc;
        t3ins(acc, rowg0 + row, v0,i0,v1,i1,v2,i2);  // identical across half
      }
    }
  } else {
    // f32 fallback: lane-owns-row streaming (correctness-first)
    const float* encb = (const float*)p.enc + ((size_t)b*N_ + (size_t)seg*SEGROWS_)*HD_;
    for (int row=tid; row<SEGROWS_; row+=256){
      gf4 rp = (gf4)(encb + (size_t)row*HD_);
      float acc = 0.f;
      #pragma unroll 8
      for (int k=0;k<64;k++){
        f32x4 v = rp[k];
        const float* qk = &qs[k*4];
        acc = fmaf(v.x, qk[0], acc);
        acc = fmaf(v.y, qk[1], acc);
        acc = fmaf(v.z, qk[2], acc);
        acc = fmaf(v.w, qk[3], acc);
      }
      lbuf[row] = acc;
      t3ins(acc, rowg0 + row, v0,i0,v1,i1,v2,i2);
    }
  }

  // keep one copy per disjoint row-set, then single exchange merge
  if constexpr (!F32){
    if (kl!=0){ v0=v1=v2=-3.4e38f; i0=i1=i2=-1; }
    float w0=__shfl_xor(v0,32,64), w1=__shfl_xor(v1,32,64), w2=__shfl_xor(v2,32,64);
    int   j0=__shfl_xor(i0,32,64), j1=__shfl_xor(i1,32,64), j2=__shfl_xor(i2,32,64);
    t3ins(w0,j0, v0,i0,v1,i1,v2,i2);
    t3ins(w1,j1, v0,i0,v1,i1,v2,i2);
    t3ins(w2,j2, v0,i0,v1,i1,v2,i2);
  } else {
    #pragma unroll
    for (int d=1; d<64; d<<=1){
      float w0=__shfl_xor(v0,d,64), w1=__shfl_xor(v1,d,64), w2=__shfl_xor(v2,d,64);
      int   j0=__shfl_xor(i0,d,64), j1=__shfl_xor(i1,d,64), j2=__shfl_xor(i2,d,64);
      t3ins(w0,j0, v0,i0,v1,i1,v2,i2);
      t3ins(w1,j1, v0,i0,v1,i1,v2,i2);
      t3ins(w2,j2, v0,i0,v1,i1,v2,i2);
    }
  }
  if (l==0){
    sv[wave][0]=v0; sv[wave][1]=v1; sv[wave][2]=v2;
    si[wave][0]=i0; si[wave][1]=i1; si[wave][2]=i2;
  }
  __syncthreads();

  if (tid==0){
    float w0=-3.4e38f,w1=-3.4e38f,w2=-3.4e38f; int j0=-1,j1=-1,j2=-1;
    for (int s=0;s<4;s++)
      for (int k=0;k<3;k++)
        t3ins(sv[s][k],si[s][k],w0,j0,w1,j1,w2,j2);
    float* pv = g_pval + (b*SEGS_+seg)*3;
    int*   pi = g_pidx + (b*SEGS_+seg)*3;
    pv[0]=w0; pv[1]=w1; pv[2]=w2;
    pi[0]=j0; pi[1]=j1; pi[2]=j2;
  }

  // coalesced logits flush
  const size_t obase = (size_t)t*B_*N_ + (size_t)b*N_ + (size_t)seg*SEGROWS_;
  if constexpr (!F32){
    u32* o4 = (u32*)((u16*)p.out + obase);
    o4[tid] = (u32)f2bf(lbuf[2*tid]) | ((u32)f2bf(lbuf[2*tid+1])<<16);
  } else {
    float2* o2 = (float2*)((float*)p.out + obase);
    o2[tid] = make_float2(lbuf[2*tid], lbuf[2*tid+1]);
  }
}

__global__ __launch_bounds__(256) void k_logits(P p, int t)
{
  __shared__ float qs[HD_];
  __shared__ float lbuf[SEGROWS_];
  __shared__ float sv[4][3];
  __shared__ int   si[4][3];
  const int b   = blockIdx.x >> 4;
  const int seg = blockIdx.x & 15;
  if (g_isf32) logits_b<true >(p, t, b, seg, qs, lbuf, sv, si);
  else         logits_b<false>(p, t, b, seg, qs, lbuf, sv, si);
}

// ---- K3: final merge for the last step's indices ----
template<bool F32>
__device__ void final_b(const P& p, int b)
{
  if (threadIdx.x==0){
    float v0=-3.4e38f,v1=-3.4e38f,v2=-3.4e38f; int i0=-1,i1=-1,i2=-1;
    const float* pv = g_pval + b*SEGS_*3;
    const int*   pi = g_pidx + b*SEGS_*3;
    for (int s=0;s<SEGS_*3;s++) t3ins(pv[s],pi[s],v0,i0,v1,i1,v2,i2);
    const size_t ib = (size_t)T_*B_*N_ + (size_t)(T_-1)*B_*3 + (size_t)b*3;
    st1<F32>(p.out, ib+0, (float)i0);
    st1<F32>(p.out, ib+1, (float)i1);
    st1<F32>(p.out, ib+2, (float)i2);
  }
}

__global__ void k_final(P p)
{
  if (g_isf32) final_b<true >(p, blockIdx.x);
  else         final_b<false>(p, blockIdx.x);
}

extern "C" void kernel_launch(void* const* d_in, const int* in_sizes, int n_in,
                              void* d_out, int out_size, void* d_ws, size_t ws_size,
                              hipStream_t stream)
{
  (void)in_sizes; (void)n_in; (void)out_size; (void)d_ws; (void)ws_size;
  P p;
  p.enc = d_in[0];
  p.h0  = d_in[1];
  p.c0  = d_in[2];
  // d_in[3] end_node_embed: unused in prediction mode
  p.x0  = d_in[4];
  p.Wih = d_in[5];
  p.bih = d_in[6];
  p.Whh = d_in[7];
  p.bhh = d_in[8];
  p.Wq  = d_in[9];
  p.bq  = d_in[10];
  // d_in[11] max_steps == 10 (fixed by setup_inputs)
  p.out = d_out;

  k_probe<<<dim3(1),dim3(64),0,stream>>>(p.enc);

  for (int t=0;t<T_;t++){
    k_lstm  <<<dim3(B_),        dim3(256),0,stream>>>(p, t);
    k_logits<<<dim3(B_*SEGS_),  dim3(256),0,stream>>>(p, t);
  }
  k_final<<<dim3(B_),dim3(64),0,stream>>>(p);
}